// Round 5
// baseline (131.052 us; speedup 1.0000x reference)
//
#include <hip/hip_runtime.h>

// B=16, C=64, H=256, W=256, K=2 non-overlapping vector max-pool.
// p = sqrt(u^2+v^2); per 2x2 window pick (u,v) at argmax(p), first-max.
// sqrt monotonic -> compare squared magnitudes; strict > keeps first-max.
//
// R4: copy-bench structure — grid-stride, 2048 blocks x 256 threads,
// 8 iterations/thread, plain float4 stores (no nt), launch_bounds(256,8)
// to keep VGPR<=64 so all 8 waves/SIMD stay resident.

typedef float f32x4 __attribute__((ext_vector_type(4)));

#define BC (16 * 64)
#define W_IN 256
#define IN_PLANE (256 * 256)
#define W_OUT 128
#define H_OUT 128
#define OUT_PLANE (W_OUT * H_OUT)
#define QUADS_PER_ROW (W_OUT / 4)                  // 32
#define N_ITEMS (BC * H_OUT * QUADS_PER_ROW)       // 4,194,304
#define NBLOCKS 2048
#define NTHREADS 256
#define GSTRIDE (NBLOCKS * NTHREADS)               // 524,288 -> 8 iterations

struct UV { float u, v; };

__device__ __forceinline__ UV pick2x2(float ua, float ub, float uc, float ud,
                                      float va, float vb, float vc, float vd) {
  // candidate order: TL(a), TR(b), BL(c), BR(d) — first-max via strict >
  float ma = ua * ua + va * va;
  float mb = ub * ub + vb * vb;
  float mc = uc * uc + vc * vc;
  float md = ud * ud + vd * vd;
  float bm = ma, bu = ua, bv = va;
  if (mb > bm) { bm = mb; bu = ub; bv = vb; }
  if (mc > bm) { bm = mc; bu = uc; bv = vc; }
  if (md > bm) { bm = md; bu = ud; bv = vd; }
  return {bu, bv};
}

__global__ __launch_bounds__(NTHREADS, 8) void vector_maxpool_kernel(
    const float* __restrict__ u, const float* __restrict__ v,
    float* __restrict__ uo, float* __restrict__ vo) {
  int tid0 = blockIdx.x * blockDim.x + threadIdx.x;

  for (int item = tid0; item < N_ITEMS; item += GSTRIDE) {
    int q  = item & (QUADS_PER_ROW - 1);   // quad within output row [0,32)
    int ho = (item >> 5) & (H_OUT - 1);    // output row [0,128)
    int bc = item >> 12;                   // fused b*c [0,1024)

    size_t in_base = (size_t)bc * IN_PLANE + (size_t)(2 * ho) * W_IN + (size_t)q * 8;

    const f32x4 u00 = *(const f32x4*)(u + in_base);
    const f32x4 u01 = *(const f32x4*)(u + in_base + 4);
    const f32x4 u10 = *(const f32x4*)(u + in_base + W_IN);
    const f32x4 u11 = *(const f32x4*)(u + in_base + W_IN + 4);
    const f32x4 v00 = *(const f32x4*)(v + in_base);
    const f32x4 v01 = *(const f32x4*)(v + in_base + 4);
    const f32x4 v10 = *(const f32x4*)(v + in_base + W_IN);
    const f32x4 v11 = *(const f32x4*)(v + in_base + W_IN + 4);

    UV a = pick2x2(u00.x, u00.y, u10.x, u10.y, v00.x, v00.y, v10.x, v10.y);
    UV b = pick2x2(u00.z, u00.w, u10.z, u10.w, v00.z, v00.w, v10.z, v10.w);
    UV c = pick2x2(u01.x, u01.y, u11.x, u11.y, v01.x, v01.y, v11.x, v11.y);
    UV d = pick2x2(u01.z, u01.w, u11.z, u11.w, v01.z, v01.w, v11.z, v11.w);

    f32x4 uout = {a.u, b.u, c.u, d.u};
    f32x4 vout = {a.v, b.v, c.v, d.v};

    size_t out_idx = (size_t)bc * OUT_PLANE + (size_t)ho * W_OUT + (size_t)q * 4;
    *(f32x4*)(uo + out_idx) = uout;
    *(f32x4*)(vo + out_idx) = vout;
  }
}

extern "C" void kernel_launch(void* const* d_in, const int* in_sizes, int n_in,
                              void* d_out, int out_size, void* d_ws, size_t ws_size,
                              hipStream_t stream) {
  const float* u = (const float*)d_in[0];
  const float* v = (const float*)d_in[1];
  float* uo = (float*)d_out;
  float* vo = uo + (size_t)BC * OUT_PLANE;

  vector_maxpool_kernel<<<NBLOCKS, NTHREADS, 0, stream>>>(u, v, uo, vo);
}

// Round 6
// 125.855 us; speedup vs baseline: 1.0413x; 1.0413x over previous
//
#include <hip/hip_runtime.h>

// B=16, C=64, H=256, W=256, K=2 non-overlapping vector max-pool.
// p = sqrt(u^2+v^2); per 2x2 window pick (u,v) at argmax(p), first-max.
// sqrt monotonic -> compare squared magnitudes; strict > keeps first-max.
//
// R5: back to R0's winning structure (1 thread per 2 output pixels, one-shot
// grid, float2 stores) + sched_group_barrier clustering so all 4 dwordx4
// loads are issued back-to-back (R0's VGPR=16 forced pairwise
// load/waitcnt/consume batching). Bytes are at the floor: FETCH=268MB is the
// L3-capacity limit (256/537), WRITE=134MB exact.

typedef float f32x4 __attribute__((ext_vector_type(4)));
typedef float f32x2 __attribute__((ext_vector_type(2)));

#define BC (16 * 64)
#define W_IN 256
#define IN_PLANE (256 * 256)
#define W_OUT 128
#define H_OUT 128
#define OUT_PLANE (W_OUT * H_OUT)
#define PAIRS_PER_ROW (W_OUT / 2)                  // 64
#define N_THREADS (BC * H_OUT * PAIRS_PER_ROW)     // 8,388,608

struct UV { float u, v; };

__device__ __forceinline__ UV pick2x2(float ua, float ub, float uc, float ud,
                                      float va, float vb, float vc, float vd) {
  // candidate order: TL(a), TR(b), BL(c), BR(d) — first-max via strict >
  float ma = ua * ua + va * va;
  float mb = ub * ub + vb * vb;
  float mc = uc * uc + vc * vc;
  float md = ud * ud + vd * vd;
  float bm = ma, bu = ua, bv = va;
  if (mb > bm) { bm = mb; bu = ub; bv = vb; }
  if (mc > bm) { bm = mc; bu = uc; bv = vc; }
  if (md > bm) { bm = md; bu = ud; bv = vd; }
  return {bu, bv};
}

__global__ __launch_bounds__(256) void vector_maxpool_kernel(
    const float* __restrict__ u, const float* __restrict__ v,
    float* __restrict__ uo, float* __restrict__ vo) {
  int tid = blockIdx.x * blockDim.x + threadIdx.x;

  int wp = tid & (PAIRS_PER_ROW - 1);        // pair index within row [0,64)
  int ho = (tid >> 6) & (H_OUT - 1);         // output row [0,128)
  int bc = tid >> 13;                        // fused b*c [0,1024)

  size_t in_base = (size_t)bc * IN_PLANE + (size_t)(2 * ho) * W_IN + (size_t)wp * 4;

  const f32x4 u0 = *(const f32x4*)(u + in_base);          // top row, 4 cols
  const f32x4 u1 = *(const f32x4*)(u + in_base + W_IN);   // bottom row
  const f32x4 v0 = *(const f32x4*)(v + in_base);
  const f32x4 v1 = *(const f32x4*)(v + in_base + W_IN);

  // Force all 4 VMEM reads to issue back-to-back before any VALU consumes
  // them (without this, VGPR-minimizing codegen batches loads in pairs).
  __builtin_amdgcn_sched_group_barrier(0x20 /*VMEM_READ*/, 4, 0);

  UV a = pick2x2(u0.x, u0.y, u1.x, u1.y, v0.x, v0.y, v1.x, v1.y);
  UV b = pick2x2(u0.z, u0.w, u1.z, u1.w, v0.z, v0.w, v1.z, v1.w);

  f32x2 uout = {a.u, b.u};
  f32x2 vout = {a.v, b.v};

  size_t out_idx = (size_t)bc * OUT_PLANE + (size_t)ho * W_OUT + (size_t)wp * 2;
  *(f32x2*)(uo + out_idx) = uout;
  *(f32x2*)(vo + out_idx) = vout;
}

extern "C" void kernel_launch(void* const* d_in, const int* in_sizes, int n_in,
                              void* d_out, int out_size, void* d_ws, size_t ws_size,
                              hipStream_t stream) {
  const float* u = (const float*)d_in[0];
  const float* v = (const float*)d_in[1];
  float* uo = (float*)d_out;
  float* vo = uo + (size_t)BC * OUT_PLANE;

  int threads = 256;
  int blocks = N_THREADS / threads;  // 32768
  vector_maxpool_kernel<<<blocks, threads, 0, stream>>>(u, v, uo, vo);
}

// Round 7
// 123.058 us; speedup vs baseline: 1.0650x; 1.0227x over previous
//
#include <hip/hip_runtime.h>

// B=16, C=64, H=256, W=256, K=2 non-overlapping vector max-pool.
// p = sqrt(u^2+v^2); per 2x2 window pick (u,v) at argmax(p), first-max.
// sqrt monotonic -> compare squared magnitudes; strict > keeps first-max.
//
// R6: exact R0 structure (best: 124.3 us) + non-temporal stores ONLY.
// A/B test: if the MALL/L3 service path is the limiter, bypassing it for
// the 134 MB of writes should give ~-10%. If neutral -> streaming roofline.

typedef float f32x4 __attribute__((ext_vector_type(4)));
typedef float f32x2 __attribute__((ext_vector_type(2)));

#define BC (16 * 64)
#define W_IN 256
#define IN_PLANE (256 * 256)
#define W_OUT 128
#define H_OUT 128
#define OUT_PLANE (W_OUT * H_OUT)
#define PAIRS_PER_ROW (W_OUT / 2)                  // 64
#define N_THREADS (BC * H_OUT * PAIRS_PER_ROW)     // 8,388,608

struct UV { float u, v; };

__device__ __forceinline__ UV pick2x2(float ua, float ub, float uc, float ud,
                                      float va, float vb, float vc, float vd) {
  // candidate order: TL(a), TR(b), BL(c), BR(d) — first-max via strict >
  float ma = ua * ua + va * va;
  float mb = ub * ub + vb * vb;
  float mc = uc * uc + vc * vc;
  float md = ud * ud + vd * vd;
  float bm = ma, bu = ua, bv = va;
  if (mb > bm) { bm = mb; bu = ub; bv = vb; }
  if (mc > bm) { bm = mc; bu = uc; bv = vc; }
  if (md > bm) { bm = md; bu = ud; bv = vd; }
  return {bu, bv};
}

__global__ __launch_bounds__(256) void vector_maxpool_kernel(
    const float* __restrict__ u, const float* __restrict__ v,
    float* __restrict__ uo, float* __restrict__ vo) {
  int tid = blockIdx.x * blockDim.x + threadIdx.x;

  int wp = tid & (PAIRS_PER_ROW - 1);        // pair index within row [0,64)
  int ho = (tid >> 6) & (H_OUT - 1);         // output row [0,128)
  int bc = tid >> 13;                        // fused b*c [0,1024)

  size_t in_base = (size_t)bc * IN_PLANE + (size_t)(2 * ho) * W_IN + (size_t)wp * 4;

  const f32x4 u0 = *(const f32x4*)(u + in_base);          // top row, 4 cols
  const f32x4 u1 = *(const f32x4*)(u + in_base + W_IN);   // bottom row
  const f32x4 v0 = *(const f32x4*)(v + in_base);
  const f32x4 v1 = *(const f32x4*)(v + in_base + W_IN);

  UV a = pick2x2(u0.x, u0.y, u1.x, u1.y, v0.x, v0.y, v1.x, v1.y);
  UV b = pick2x2(u0.z, u0.w, u1.z, u1.w, v0.z, v0.w, v1.z, v1.w);

  f32x2 uout = {a.u, b.u};
  f32x2 vout = {a.v, b.v};

  size_t out_idx = (size_t)bc * OUT_PLANE + (size_t)ho * W_OUT + (size_t)wp * 2;
  __builtin_nontemporal_store(uout, (f32x2*)(uo + out_idx));
  __builtin_nontemporal_store(vout, (f32x2*)(vo + out_idx));
}

extern "C" void kernel_launch(void* const* d_in, const int* in_sizes, int n_in,
                              void* d_out, int out_size, void* d_ws, size_t ws_size,
                              hipStream_t stream) {
  const float* u = (const float*)d_in[0];
  const float* v = (const float*)d_in[1];
  float* uo = (float*)d_out;
  float* vo = uo + (size_t)BC * OUT_PLANE;

  int threads = 256;
  int blocks = N_THREADS / threads;  // 32768
  vector_maxpool_kernel<<<blocks, threads, 0, stream>>>(u, v, uo, vo);
}